// Round 5
// baseline (619.671 us; speedup 1.0000x reference)
//
#include <hip/hip_runtime.h>
#include <cstdint>
#include <cstddef>

// SOM BMU: dists[b,m] = ||x[b] - W[:,m] + eps||, argmin/min over m.
//   sq = rowTerm[b] + colTerm[m] - 2*dot(x[b],W[:,m]) + D*eps^2
// dot via split-precision f16 MFMA (xh.wh + xh.wl + xl.wh, ~2^-22 rel err).
// Pre-swizzled staging format (written by prep):
//   addr16(r,c) = (r>>4)*32768 + (c>>2)*1024 + (c&3)*256 + (r&15)*16
// R9:  XCD-aware block swizzle (kept). R10: prep 2304 blocks (kept).
// R11: colPart epilogue-sum, no memset launch (non-som 110.8->84.8us; kept).
//      1-blk/CU 128x256 dbuf: REGRESSED (294us, util 30%) - no cross-cover.
// R12: 2-blk/CU 128x128 counted-vmcnt dbuf: REGRESSED (225us, util 41%) -
//      halved per-step MFMA work, same per-step latency; intensity loss.
// R13 (this round): R2's PROVEN som body (128x256, 96 MFMA/wave/step, simple
//      2-barrier loop, 48KB LDS, measured 188us @ util 51%) at THREE blocks/CU
//      (3x48=144KB <= 160KB, VGPR 116 <= 512/3). Model: per-CU MFMA floor
//      ~99us; R2's loss = ~900cy staging drain per step, covered only by 1
//      other block. 3 out-of-phase blocks cover better, and the 4-blk/CU grid
//      runs 3+1 instead of 2+2. Single variable vs measured R2 config.
// Argmin via packed u64 key (dist_bits<<32 | m) + atomicMin.

#define B_  2048
#define D_  1024
#define M_  16384
#define EPS_ 1e-6f

typedef _Float16 v8h __attribute__((ext_vector_type(8)));
typedef float    v4f __attribute__((ext_vector_type(4)));

static __device__ __forceinline__ unsigned long long umin64(unsigned long long a,
                                                            unsigned long long b) {
    return a < b ? a : b;
}

// swizzled 16B-chunk address: row r, k-chunk c (8 f16 per chunk)
static __device__ __forceinline__ size_t addr16(int r, int c) {
    return (size_t)(r >> 4) * 32768 + (size_t)(c >> 2) * 1024 +
           (size_t)(c & 3) * 256 + (size_t)(r & 15) * 16;
}

#define GLDS16(g, l)                                                            \
    __builtin_amdgcn_global_load_lds(                                           \
        (const __attribute__((address_space(1))) void*)(g),                     \
        (__attribute__((address_space(3))) void*)(l), 16, 0, 0)

// ---------- fused prep ----------
// blocks 0..2047:    W-path. block = (col-group mg = blk>>3: 64 cols) x
//                    (d-chunk dc = blk&7: 128 d). One col per thread per wave,
//                    4 waves each cover 32 d. Writes colPart[dc][m] (no atomics).
// blocks 2048..2303: x-path. 8 rows each, one row per 32-lane half-wave.
//                    x-block 0 also inits keys + loss slot.
__global__ __launch_bounds__(256) void prep(
    const float* __restrict__ x, const float* __restrict__ W,
    _Float16* __restrict__ xh, _Float16* __restrict__ xl,
    _Float16* __restrict__ wth, _Float16* __restrict__ wtl,
    float* __restrict__ rowTerm, float* __restrict__ colPart,
    unsigned long long* __restrict__ keys, float* __restrict__ out)
{
    const int t = threadIdx.x;
    const int blk = blockIdx.x;
    if (blk < 2048) {
        __shared__ float cpart[4][64];
        const int mg = blk >> 3, dc = blk & 7;
        const int m_local = t & 63;
        const int wq = t >> 6;
        const int m = mg * 64 + m_local;
        const float* wp = W + m;
        float part = 0.f;
        #pragma unroll
        for (int cl = 0; cl < 4; ++cl) {
            const int c = dc * 16 + wq * 4 + cl;     // k-chunk (8 d each)
            const int d0 = c * 8;
            float vv[8];
            #pragma unroll
            for (int e = 0; e < 8; ++e)
                vv[e] = wp[(size_t)(d0 + e) * M_];   // wave = 256B coalesced
            v8h h, l;
            #pragma unroll
            for (int e = 0; e < 8; ++e) {
                _Float16 hi = (_Float16)vv[e];
                h[e] = hi; l[e] = (_Float16)(vv[e] - (float)hi);
                part += vv[e] * vv[e] - 2.0f * EPS_ * vv[e];
            }
            const size_t a = addr16(m, c);
            *(v8h*)((char*)wth + a) = h;             // lanes 0-15: 256B contig
            *(v8h*)((char*)wtl + a) = l;
        }
        cpart[wq][m_local] = part;
        __syncthreads();
        if (t < 64)
            colPart[(size_t)dc * M_ + mg * 64 + t] =
                cpart[0][t] + cpart[1][t] + cpart[2][t] + cpart[3][t];
    } else {
        const int xb = blk - 2048;
        const int w = t >> 6, L = t & 63;
        const int hl = L & 31;
        const int r = xb * 8 + 2 * w + (L >> 5);
        const float* xr = x + (size_t)r * D_;
        float part = 0.f;
        #pragma unroll
        for (int i = 0; i < 4; ++i) {
            const int c = 32 * i + hl;               // half-wave = 1KB coalesced
            float4 q1 = *(const float4*)(xr + 8 * c);
            float4 q2 = *(const float4*)(xr + 8 * c + 4);
            float vv[8] = {q1.x, q1.y, q1.z, q1.w, q2.x, q2.y, q2.z, q2.w};
            v8h h, l;
            #pragma unroll
            for (int e = 0; e < 8; ++e) {
                _Float16 hi = (_Float16)vv[e];
                h[e] = hi; l[e] = (_Float16)(vv[e] - (float)hi);
                part += vv[e] * vv[e] + 2.0f * EPS_ * vv[e];
            }
            const size_t a = addr16(r, c);
            *(v8h*)((char*)xh + a) = h;
            *(v8h*)((char*)xl + a) = l;
        }
        #pragma unroll
        for (int msk = 1; msk <= 16; msk <<= 1)
            part += __shfl_xor(part, msk, 64);       // stays within 32-lane half
        if (hl == 0) rowTerm[r] = part;
        if (xb == 0) {
            for (int i = t; i < B_; i += 256) keys[i] = ~0ull;
            if (t == 0) out[3 * B_] = 0.f;
        }
    }
}

// ---------- main MFMA distance GEMM + argmin ----------
// 128x256 block tile, 4 waves (2x2, each 64 rows x 128 cols), BK=32.
// R2's proven 2-barrier body; 48KB static LDS; 3 blocks/CU for stall cover.
__global__ __launch_bounds__(256, 3) void som_mfma(
    const _Float16* __restrict__ xh, const _Float16* __restrict__ xl,
    const _Float16* __restrict__ wth, const _Float16* __restrict__ wtl,
    const float* __restrict__ rowTerm, const float* __restrict__ colPart,
    unsigned long long* __restrict__ keys)
{
    __shared__ __align__(16) char smem[49152];   // Ah 8K | Al 8K | Bh 16K | Bl 16K
    _Float16* Ah = (_Float16*)smem;
    _Float16* Al = (_Float16*)(smem + 8192);
    _Float16* Bh = (_Float16*)(smem + 16384);
    _Float16* Bl = (_Float16*)(smem + 32768);

    const int t = threadIdx.x;
    const int g = blockIdx.x;
    // XCD-aware: round-robin dispatch puts g on XCD g&7; all 16 row-blocks of
    // a slab share g&7 -> same XCD L2. bijective: g=(slab&7)+8*row+128*(slab>>3)
    const int slab = (g & 7) + 8 * (g >> 7);
    const int cb = slab * 256;
    const int rb = ((g >> 3) & 15) * 128;
    const int L = t & 63, w = t >> 6;
    const int wro = (w >> 1) * 64;
    const int wco = (w & 1) * 128;
    const int c16 = L & 15, kq = L >> 4;

    // staging: per call, wave w covers one 16-row group (1 KB linear)
    const int lane16 = L * 16;
    const int ldsw = w * 1024;                    // wave-uniform LDS base
    const size_t abase0 = (size_t)((rb >> 4) + w) * 32768 + lane16;
    const size_t abase1 = abase0 + 4ull * 32768;
    const size_t bbase0 = (size_t)((cb >> 4) + w) * 32768 + lane16;
    const size_t bbase1 = bbase0 + 4ull * 32768;
    const size_t bbase2 = bbase0 + 8ull * 32768;
    const size_t bbase3 = bbase0 + 12ull * 32768;

    const char* pxh = (const char*)xh;
    const char* pxl = (const char*)xl;
    const char* pwh = (const char*)wth;
    const char* pwl = (const char*)wtl;

    v4f acc[4][8];
    #pragma unroll
    for (int i = 0; i < 4; ++i)
        #pragma unroll
        for (int j = 0; j < 8; ++j) acc[i][j] = (v4f){0.f, 0.f, 0.f, 0.f};

    // fragment read offsets (f16 units): group grp -> grp*512 + lofs
    // lofs: chunk (L>>4)*128 + row (L&15)*8 -> 16-lane groups on 16
    // consecutive slots (conflict-free, measured 0)
    const int lofs = kq * 128 + c16 * 8;
    int ia[4], ibx[8];
    #pragma unroll
    for (int i = 0; i < 4; ++i) ia[i] = ((wro >> 4) + i) * 512 + lofs;
    #pragma unroll
    for (int j = 0; j < 8; ++j) ibx[j] = ((wco >> 4) + j) * 512 + lofs;

    for (int S = 0; S < 32; ++S) {
        const size_t ko = (size_t)S * 1024;
        __syncthreads();
        GLDS16(pxh + abase0 + ko, smem + ldsw);
        GLDS16(pxh + abase1 + ko, smem + 4096 + ldsw);
        GLDS16(pxl + abase0 + ko, smem + 8192 + ldsw);
        GLDS16(pxl + abase1 + ko, smem + 12288 + ldsw);
        GLDS16(pwh + bbase0 + ko, smem + 16384 + ldsw);
        GLDS16(pwh + bbase1 + ko, smem + 20480 + ldsw);
        GLDS16(pwh + bbase2 + ko, smem + 24576 + ldsw);
        GLDS16(pwh + bbase3 + ko, smem + 28672 + ldsw);
        GLDS16(pwl + bbase0 + ko, smem + 32768 + ldsw);
        GLDS16(pwl + bbase1 + ko, smem + 36864 + ldsw);
        GLDS16(pwl + bbase2 + ko, smem + 40960 + ldsw);
        GLDS16(pwl + bbase3 + ko, smem + 45056 + ldsw);
        __syncthreads();

        v8h ah[4], al4[4], bh4[4], bl4[4];
        #pragma unroll
        for (int i = 0; i < 4; ++i) {
            ah[i]  = *(const v8h*)(Ah + ia[i]);
            al4[i] = *(const v8h*)(Al + ia[i]);
        }
        #pragma unroll
        for (int j = 0; j < 4; ++j) {
            bh4[j] = *(const v8h*)(Bh + ibx[j]);
            bl4[j] = *(const v8h*)(Bl + ibx[j]);
        }
        #pragma unroll
        for (int i = 0; i < 4; ++i)
            #pragma unroll
            for (int j = 0; j < 4; ++j) {
                acc[i][j] = __builtin_amdgcn_mfma_f32_16x16x32_f16(ah[i],  bh4[j], acc[i][j], 0, 0, 0);
                acc[i][j] = __builtin_amdgcn_mfma_f32_16x16x32_f16(ah[i],  bl4[j], acc[i][j], 0, 0, 0);
                acc[i][j] = __builtin_amdgcn_mfma_f32_16x16x32_f16(al4[i], bh4[j], acc[i][j], 0, 0, 0);
            }
        #pragma unroll
        for (int j = 0; j < 4; ++j) {
            bh4[j] = *(const v8h*)(Bh + ibx[j + 4]);
            bl4[j] = *(const v8h*)(Bl + ibx[j + 4]);
        }
        #pragma unroll
        for (int i = 0; i < 4; ++i)
            #pragma unroll
            for (int j = 0; j < 4; ++j) {
                acc[i][j+4] = __builtin_amdgcn_mfma_f32_16x16x32_f16(ah[i],  bh4[j], acc[i][j+4], 0, 0, 0);
                acc[i][j+4] = __builtin_amdgcn_mfma_f32_16x16x32_f16(ah[i],  bl4[j], acc[i][j+4], 0, 0, 0);
                acc[i][j+4] = __builtin_amdgcn_mfma_f32_16x16x32_f16(al4[i], bh4[j], acc[i][j+4], 0, 0, 0);
            }
    }

    // epilogue: C/D layout col=lane&15, row=(lane>>4)*4+reg  [verified m89/m91]
    float cT[8];
    #pragma unroll
    for (int j = 0; j < 8; ++j) {
        const int col = cb + wco + j * 16 + c16;
        float s = 0.f;
        #pragma unroll
        for (int p = 0; p < 8; ++p) s += colPart[(size_t)p * M_ + col];
        cT[j] = s;
    }
    const float de2 = (float)D_ * EPS_ * EPS_;
    #pragma unroll
    for (int i = 0; i < 4; ++i) {
        #pragma unroll
        for (int r = 0; r < 4; ++r) {
            int row_g = rb + wro + i * 16 + kq * 4 + r;
            float rt = rowTerm[row_g];
            unsigned long long best = ~0ull;
            #pragma unroll
            for (int j = 0; j < 8; ++j) {
                float sq = rt + cT[j] - 2.0f * acc[i][j][r] + de2;
                sq = fmaxf(sq, 0.0f);
                float dist = sqrtf(sq);
                unsigned long long key =
                    ((unsigned long long)__float_as_uint(dist) << 32) |
                    (unsigned int)(cb + wco + j * 16 + c16);
                best = umin64(best, key);
            }
            #pragma unroll
            for (int m = 1; m <= 8; m <<= 1) {
                unsigned long long o =
                    (unsigned long long)__shfl_xor((long long)best, m, 64);
                best = umin64(best, o);
            }
            if (c16 == 0) atomicMin(&keys[row_g], best);
        }
    }
}

// ---------- fallback fp32 path (used only if ws too small) ----------
__global__ void row_stats(const float* __restrict__ x, float* __restrict__ rowTerm) {
    int b = blockIdx.x;
    const float* xr = x + (size_t)b * D_;
    int t = threadIdx.x;
    float acc = 0.f;
    for (int i = t; i < D_; i += 256) {
        float v = xr[i];
        acc += v * v + 2.0f * EPS_ * v;
    }
    for (int off = 32; off; off >>= 1) acc += __shfl_down(acc, off, 64);
    __shared__ float s[4];
    if ((t & 63) == 0) s[t >> 6] = acc;
    __syncthreads();
    if (t == 0) rowTerm[b] = s[0] + s[1] + s[2] + s[3];
}

__global__ void col_stats(const float* __restrict__ w, float* __restrict__ colTerm) {
    int m = blockIdx.x * 256 + threadIdx.x;
    int d0 = blockIdx.y * 64;
    const float* p = w + (size_t)d0 * M_ + m;
    float acc = 0.f;
    #pragma unroll 8
    for (int d = 0; d < 64; ++d) {
        float v = p[(size_t)d * M_];
        acc += v * v - 2.0f * EPS_ * v;
    }
    atomicAdd(&colTerm[m], acc);
}

__global__ __launch_bounds__(256, 2) void som_gemm(
    const float* __restrict__ A, const float* __restrict__ Wt,
    const float* __restrict__ rowTerm, const float* __restrict__ colTerm,
    unsigned long long* __restrict__ keys)
{
    __shared__ float As[8][128];
    __shared__ float Bs[8][128];
    const int t  = threadIdx.x;
    const int rb = blockIdx.y * 128;
    const int cb = blockIdx.x * 128;
    const int tx = t & 15;
    const int ty = t >> 4;
    float acc[8][8];
    #pragma unroll
    for (int i = 0; i < 8; ++i)
        #pragma unroll
        for (int j = 0; j < 8; ++j) acc[i][j] = 0.f;
    const int la_row = t >> 1, la_k = (t & 1) * 4;
    const int lb_k = t >> 5, lb_n = (t & 31) * 4;
    const float* Aptr = A + (size_t)(rb + la_row) * D_ + la_k;
    const float* Bptr = Wt + (size_t)lb_k * M_ + cb + lb_n;
    for (int k0 = 0; k0 < D_; k0 += 8) {
        float4 av = *(const float4*)(Aptr + k0);
        float4 bv = *(const float4*)(Bptr + (size_t)k0 * M_);
        __syncthreads();
        As[la_k + 0][la_row] = av.x;
        As[la_k + 1][la_row] = av.y;
        As[la_k + 2][la_row] = av.z;
        As[la_k + 3][la_row] = av.w;
        *(float4*)&Bs[lb_k][lb_n] = bv;
        __syncthreads();
        #pragma unroll
        for (int k = 0; k < 8; ++k) {
            float a[8], b[8];
            #pragma unroll
            for (int i = 0; i < 8; ++i) a[i] = As[k][ty * 8 + i];
            #pragma unroll
            for (int j = 0; j < 8; ++j) b[j] = Bs[k][tx * 8 + j];
            #pragma unroll
            for (int i = 0; i < 8; ++i)
                #pragma unroll
                for (int j = 0; j < 8; ++j) acc[i][j] += a[i] * b[j];
        }
    }
    float rT[8], cT[8];
    #pragma unroll
    for (int i = 0; i < 8; ++i) rT[i] = rowTerm[rb + ty * 8 + i];
    #pragma unroll
    for (int j = 0; j < 8; ++j) cT[j] = colTerm[cb + tx * 8 + j];
    const float de2 = (float)D_ * EPS_ * EPS_;
    #pragma unroll
    for (int i = 0; i < 8; ++i) {
        unsigned long long best = ~0ull;
        #pragma unroll
        for (int j = 0; j < 8; ++j) {
            float sq = rT[i] + cT[j] - 2.0f * acc[i][j] + de2;
            sq = fmaxf(sq, 0.0f);
            float dist = sqrtf(sq);
            unsigned long long key =
                ((unsigned long long)__float_as_uint(dist) << 32) |
                (unsigned int)(cb + tx * 8 + j);
            best = umin64(best, key);
        }
        #pragma unroll
        for (int msk = 1; msk <= 8; msk <<= 1) {
            unsigned long long o = __shfl_xor((long long)best, msk, 64);
            best = umin64(best, (unsigned long long)o);
        }
        if (tx == 0) atomicMin(&keys[rb + ty * 8 + i], best);
    }
}

// ---------- finalize: 8 blocks of 256 rows ----------
__global__ void finalize(const unsigned long long* __restrict__ keys,
                         const float* __restrict__ loc,
                         float* __restrict__ out)
{
    int t = threadIdx.x;
    int r = blockIdx.x * 256 + t;
    unsigned long long k = keys[r];
    unsigned int idx = (unsigned int)(k & 0xFFFFFFFFu);
    float dist = __uint_as_float((unsigned int)(k >> 32));
    out[r] = (float)idx;
    out[B_ + 2 * r]     = loc[2 * idx];
    out[B_ + 2 * r + 1] = loc[2 * idx + 1];
    float sum = dist;
    for (int off = 32; off; off >>= 1) sum += __shfl_down(sum, off, 64);
    __shared__ float s[4];
    if ((t & 63) == 0) s[t >> 6] = sum;
    __syncthreads();
    if (t == 0) atomicAdd(&out[3 * B_], (s[0] + s[1] + s[2] + s[3]) / (float)B_);
}

extern "C" void kernel_launch(void* const* d_in, const int* in_sizes, int n_in,
                              void* d_out, int out_size, void* d_ws, size_t ws_size,
                              hipStream_t stream)
{
    const float* x   = (const float*)d_in[0];
    const float* w   = (const float*)d_in[1];
    const float* loc = (const float*)d_in[2];
    float* out = (float*)d_out;

    char* ws = (char*)d_ws;
    unsigned long long* keys = (unsigned long long*)ws;   // 16 KB
    float* rowTerm = (float*)(ws + (16 << 10));           //  8 KB
    float* colPart = (float*)(ws + (24 << 10));           // 512 KB (8 planes)
    _Float16* xh  = (_Float16*)(ws + (1ull << 20));       //  4 MB
    _Float16* xl  = (_Float16*)(ws + (5ull << 20));       //  4 MB
    _Float16* wth = (_Float16*)(ws + (9ull << 20));       // 32 MB
    _Float16* wtl = (_Float16*)(ws + (41ull << 20));      // 32 MB
    const size_t NEED = 73ull << 20;

    if (ws_size >= NEED) {
        prep<<<2304, 256, 0, stream>>>(x, w, xh, xl, wth, wtl,
                                       rowTerm, colPart, keys, out);
        som_mfma<<<1024, 256, 0, stream>>>(
            xh, xl, wth, wtl, rowTerm, colPart, keys);
    } else {
        hipMemsetAsync(keys, 0xFF, B_ * sizeof(unsigned long long), stream);
        hipMemsetAsync(colPart, 0, M_ * sizeof(float), stream);
        hipMemsetAsync(out + 3 * B_, 0, sizeof(float), stream);
        row_stats<<<B_, 256, 0, stream>>>(x, rowTerm);
        col_stats<<<dim3(M_ / 256, D_ / 64), 256, 0, stream>>>(w, colPart);
        som_gemm<<<dim3(M_ / 128, B_ / 128), 256, 0, stream>>>(
            x, w, rowTerm, colPart, keys);
    }
    finalize<<<8, 256, 0, stream>>>(keys, loc, out);
}

// Round 6
// 303.716 us; speedup vs baseline: 2.0403x; 2.0403x over previous
//
#include <hip/hip_runtime.h>
#include <cstdint>
#include <cstddef>

// SOM BMU: dists[b,m] = ||x[b] - W[:,m] + eps||, argmin/min over m.
//   sq = rowTerm[b] + colTerm[m] - 2*dot(x[b],W[:,m]) + D*eps^2
// dot via split-precision f16 MFMA (xh.wh + xh.wl + xl.wh, ~2^-22 rel err).
// Pre-swizzled staging format (written by prep):
//   addr16(r,c) = (r>>4)*32768 + (c>>2)*1024 + (c&3)*256 + (r&15)*16
// R9:  XCD swizzle (kept). R10: prep 2304 blocks (kept). R11: colPart (kept).
// R12: 128x128 counted dbuf -> 41% util: intensity-limited (32KB/step for
//      48 MFMA/wave). R13: (256,3) -> VGPR cap 170 < 180 needed -> ACC SPILL
//      (WRITE_SIZE 924MB, 532us). Lesson: 2 blocks/CU max for 64x128/wave acc.
// Calibrated model: MFMA = 4.85 CU-cyc; GLDS staging path sustains only
//      ~15-30 B/cyc/CU (R2: 51% util at 52 B/cyc demand; R4: 41% at 34).
//      => raise bytes-per-MFMA intensity: 256x256 tile = 64KB/step for
//      8x96 MFMA = 17.6 B/cyc demand.
// R14 (this round): som = 256x256, 8 waves (512thr), BK=32, full dbuf
//      2x64KB=128KB LDS, 1 block/CU (acc 128 AGPR + ~110 VGPR < 256 @ 2
//      waves/SIMD), R4's race-verified counted-vmcnt rotation:
//      {reads+96MFMA; lgkm0; barA; STAGE(S+2->cur); vmcnt(8); barB}.
//      Grid 512 = 2 exact rounds; XCD swizzle pins col-tile to XCD.
// Argmin via packed u64 key (dist_bits<<32 | m) + atomicMin.

#define B_  2048
#define D_  1024
#define M_  16384
#define EPS_ 1e-6f

typedef _Float16 v8h __attribute__((ext_vector_type(8)));
typedef float    v4f __attribute__((ext_vector_type(4)));

static __device__ __forceinline__ unsigned long long umin64(unsigned long long a,
                                                            unsigned long long b) {
    return a < b ? a : b;
}

// swizzled 16B-chunk address: row r, k-chunk c (8 f16 per chunk)
static __device__ __forceinline__ size_t addr16(int r, int c) {
    return (size_t)(r >> 4) * 32768 + (size_t)(c >> 2) * 1024 +
           (size_t)(c & 3) * 256 + (size_t)(r & 15) * 16;
}

#define GLDS16(g, l)                                                            \
    __builtin_amdgcn_global_load_lds(                                           \
        (const __attribute__((address_space(1))) void*)(g),                     \
        (__attribute__((address_space(3))) void*)(l), 16, 0, 0)

// ---------- fused prep ----------
// blocks 0..2047:    W-path. block = (col-group mg = blk>>3: 64 cols) x
//                    (d-chunk dc = blk&7: 128 d). One col per thread per wave,
//                    4 waves each cover 32 d. Writes colPart[dc][m] (no atomics).
// blocks 2048..2303: x-path. 8 rows each, one row per 32-lane half-wave.
//                    x-block 0 also inits keys + loss slot.
__global__ __launch_bounds__(256) void prep(
    const float* __restrict__ x, const float* __restrict__ W,
    _Float16* __restrict__ xh, _Float16* __restrict__ xl,
    _Float16* __restrict__ wth, _Float16* __restrict__ wtl,
    float* __restrict__ rowTerm, float* __restrict__ colPart,
    unsigned long long* __restrict__ keys, float* __restrict__ out)
{
    const int t = threadIdx.x;
    const int blk = blockIdx.x;
    if (blk < 2048) {
        __shared__ float cpart[4][64];
        const int mg = blk >> 3, dc = blk & 7;
        const int m_local = t & 63;
        const int wq = t >> 6;
        const int m = mg * 64 + m_local;
        const float* wp = W + m;
        float part = 0.f;
        #pragma unroll
        for (int cl = 0; cl < 4; ++cl) {
            const int c = dc * 16 + wq * 4 + cl;     // k-chunk (8 d each)
            const int d0 = c * 8;
            float vv[8];
            #pragma unroll
            for (int e = 0; e < 8; ++e)
                vv[e] = wp[(size_t)(d0 + e) * M_];   // wave = 256B coalesced
            v8h h, l;
            #pragma unroll
            for (int e = 0; e < 8; ++e) {
                _Float16 hi = (_Float16)vv[e];
                h[e] = hi; l[e] = (_Float16)(vv[e] - (float)hi);
                part += vv[e] * vv[e] - 2.0f * EPS_ * vv[e];
            }
            const size_t a = addr16(m, c);
            *(v8h*)((char*)wth + a) = h;             // lanes 0-15: 256B contig
            *(v8h*)((char*)wtl + a) = l;
        }
        cpart[wq][m_local] = part;
        __syncthreads();
        if (t < 64)
            colPart[(size_t)dc * M_ + mg * 64 + t] =
                cpart[0][t] + cpart[1][t] + cpart[2][t] + cpart[3][t];
    } else {
        const int xb = blk - 2048;
        const int w = t >> 6, L = t & 63;
        const int hl = L & 31;
        const int r = xb * 8 + 2 * w + (L >> 5);
        const float* xr = x + (size_t)r * D_;
        float part = 0.f;
        #pragma unroll
        for (int i = 0; i < 4; ++i) {
            const int c = 32 * i + hl;               // half-wave = 1KB coalesced
            float4 q1 = *(const float4*)(xr + 8 * c);
            float4 q2 = *(const float4*)(xr + 8 * c + 4);
            float vv[8] = {q1.x, q1.y, q1.z, q1.w, q2.x, q2.y, q2.z, q2.w};
            v8h h, l;
            #pragma unroll
            for (int e = 0; e < 8; ++e) {
                _Float16 hi = (_Float16)vv[e];
                h[e] = hi; l[e] = (_Float16)(vv[e] - (float)hi);
                part += vv[e] * vv[e] + 2.0f * EPS_ * vv[e];
            }
            const size_t a = addr16(r, c);
            *(v8h*)((char*)xh + a) = h;
            *(v8h*)((char*)xl + a) = l;
        }
        #pragma unroll
        for (int msk = 1; msk <= 16; msk <<= 1)
            part += __shfl_xor(part, msk, 64);       // stays within 32-lane half
        if (hl == 0) rowTerm[r] = part;
        if (xb == 0) {
            for (int i = t; i < B_; i += 256) keys[i] = ~0ull;
            if (t == 0) out[3 * B_] = 0.f;
        }
    }
}

// ---------- main MFMA distance GEMM + argmin ----------
// 256x256 block tile, 8 waves (4x2, each 64 rows x 128 cols), BK=32.
// Full double-buffer: 2 x 65536 B dynamic LDS (Ah16|Al16|Bh16|Bl16 per buf),
// 1 block/CU (2 waves/SIMD), counted-vmcnt rotation (no in-loop drain).
__global__ __launch_bounds__(512, 2) void som_mfma(
    const _Float16* __restrict__ xh, const _Float16* __restrict__ xl,
    const _Float16* __restrict__ wth, const _Float16* __restrict__ wtl,
    const float* __restrict__ rowTerm, const float* __restrict__ colPart,
    unsigned long long* __restrict__ keys)
{
    extern __shared__ __align__(16) char smem[];   // 2 x 64KB buffers

    const int t = threadIdx.x;
    const int g = blockIdx.x;                      // 0..511
    // XCD swizzle: 512 blocks round-robin XCD = g%8. ct = (g&7) + 8*(g>>6),
    // rt = (g>>3)&7  -> bijective; all 8 row-tiles of a col-tile share g%8.
    const int ct = (g & 7) + 8 * (g >> 6);         // col-tile 0..63
    const int rt = (g >> 3) & 7;                   // row-tile 0..7
    const int cb = ct * 256;
    const int rb = rt * 256;
    const int L = t & 63, w = t >> 6;              // wave 0..7
    const int wro = (w >> 1) * 64;                 // 4 row-groups
    const int wco = (w & 1) * 128;                 // 2 col-groups
    const int c16 = L & 15, kq = L >> 4;

    // staging: wave w stages groups {w, w+8} of each of the 4 planes (8 GLDS)
    const unsigned lane16 = (unsigned)L * 16;
    const unsigned a0 = (unsigned)((rb >> 4) + w) * 32768u + lane16;
    const unsigned a1 = a0 + 8u * 32768u;
    const unsigned b0 = (unsigned)((cb >> 4) + w) * 32768u + lane16;
    const unsigned b1 = b0 + 8u * 32768u;

    const char* pxh = (const char*)xh;
    const char* pxl = (const char*)xl;
    const char* pwh = (const char*)wth;
    const char* pwl = (const char*)wtl;

    v4f acc[4][8];
    #pragma unroll
    for (int i = 0; i < 4; ++i)
        #pragma unroll
        for (int j = 0; j < 8; ++j) acc[i][j] = (v4f){0.f, 0.f, 0.f, 0.f};

    // fragment read offsets (f16 units within a 16KB plane):
    // group grp -> grp*512 + lofs; lofs = chunk(L>>4)*128 + row(L&15)*8
    const int lofs = kq * 128 + c16 * 8;
    int ia[4], ibx[8];
    #pragma unroll
    for (int i = 0; i < 4; ++i) ia[i] = ((wro >> 4) + i) * 512 + lofs;
    #pragma unroll
    for (int j = 0; j < 8; ++j) ibx[j] = ((wco >> 4) + j) * 512 + lofs;

    // 8 staging loads for step S into buffer bsel (1KB per GLDS, lane-linear)
#define STAGE(S_, bsel)                                                         \
    do {                                                                        \
        char* _b = smem + (bsel) * 65536 + w * 1024;                            \
        const unsigned _ko = (unsigned)(S_) * 1024u;                            \
        GLDS16(pxh + (a0 + _ko), _b);                                           \
        GLDS16(pxh + (a1 + _ko), _b + 8192);                                    \
        GLDS16(pxl + (a0 + _ko), _b + 16384);                                   \
        GLDS16(pxl + (a1 + _ko), _b + 24576);                                   \
        GLDS16(pwh + (b0 + _ko), _b + 32768);                                   \
        GLDS16(pwh + (b1 + _ko), _b + 40960);                                   \
        GLDS16(pwl + (b0 + _ko), _b + 49152);                                   \
        GLDS16(pwl + (b1 + _ko), _b + 57344);                                   \
    } while (0)

    // prologue: both buffers in flight; wait buf0 (leave buf1's 8 outstanding)
    STAGE(0, 0);
    STAGE(1, 1);
    asm volatile("s_waitcnt vmcnt(8)" ::: "memory");
    __builtin_amdgcn_sched_barrier(0);
    __builtin_amdgcn_s_barrier();                 // buf0 staged for all waves
    __builtin_amdgcn_sched_barrier(0);

    for (int S = 0; S < 32; ++S) {
        const int cur = S & 1;
        const char* buf = smem + cur * 65536;
        const _Float16* Ah = (const _Float16*)(buf);
        const _Float16* Al = (const _Float16*)(buf + 16384);
        const _Float16* Bh = (const _Float16*)(buf + 32768);
        const _Float16* Bl = (const _Float16*)(buf + 49152);

        v8h ah[4], al4[4], bh4[4], bl4[4];
        #pragma unroll
        for (int i = 0; i < 4; ++i) {
            ah[i]  = *(const v8h*)(Ah + ia[i]);
            al4[i] = *(const v8h*)(Al + ia[i]);
        }
        #pragma unroll
        for (int j = 0; j < 4; ++j) {
            bh4[j] = *(const v8h*)(Bh + ibx[j]);
            bl4[j] = *(const v8h*)(Bl + ibx[j]);
        }
        #pragma unroll
        for (int i = 0; i < 4; ++i)
            #pragma unroll
            for (int j = 0; j < 4; ++j) {
                acc[i][j] = __builtin_amdgcn_mfma_f32_16x16x32_f16(ah[i],  bh4[j], acc[i][j], 0, 0, 0);
                acc[i][j] = __builtin_amdgcn_mfma_f32_16x16x32_f16(ah[i],  bl4[j], acc[i][j], 0, 0, 0);
                acc[i][j] = __builtin_amdgcn_mfma_f32_16x16x32_f16(al4[i], bh4[j], acc[i][j], 0, 0, 0);
            }
        #pragma unroll
        for (int j = 0; j < 4; ++j) {
            bh4[j] = *(const v8h*)(Bh + ibx[j + 4]);
            bl4[j] = *(const v8h*)(Bl + ibx[j + 4]);
        }
        #pragma unroll
        for (int i = 0; i < 4; ++i)
            #pragma unroll
            for (int j = 0; j < 4; ++j) {
                acc[i][j+4] = __builtin_amdgcn_mfma_f32_16x16x32_f16(ah[i],  bh4[j], acc[i][j+4], 0, 0, 0);
                acc[i][j+4] = __builtin_amdgcn_mfma_f32_16x16x32_f16(ah[i],  bl4[j], acc[i][j+4], 0, 0, 0);
                acc[i][j+4] = __builtin_amdgcn_mfma_f32_16x16x32_f16(al4[i], bh4[j], acc[i][j+4], 0, 0, 0);
            }

        // all my ds_reads of buf[cur] done -> after barrier A it is free
        asm volatile("s_waitcnt lgkmcnt(0)" ::: "memory");
        __builtin_amdgcn_sched_barrier(0);
        __builtin_amdgcn_s_barrier();             // barrier A: buf[cur] free
        __builtin_amdgcn_sched_barrier(0);

        if (S < 30) {
            STAGE(S + 2, cur);                    // refill freed buffer
            asm volatile("s_waitcnt vmcnt(8)" ::: "memory");  // S+1's 8 done
        } else {
            asm volatile("s_waitcnt vmcnt(0)" ::: "memory");  // drain tail
        }
        __builtin_amdgcn_sched_barrier(0);
        __builtin_amdgcn_s_barrier();             // barrier B: buf[cur^1] ready
        __builtin_amdgcn_sched_barrier(0);
    }
#undef STAGE

    // epilogue: C/D layout col=lane&15, row=(lane>>4)*4+reg  [verified m89/m91]
    float cT[8];
    #pragma unroll
    for (int j = 0; j < 8; ++j) {
        const int col = cb + wco + j * 16 + c16;
        float s = 0.f;
        #pragma unroll
        for (int p = 0; p < 8; ++p) s += colPart[(size_t)p * M_ + col];
        cT[j] = s;
    }
    const float de2 = (float)D_ * EPS_ * EPS_;
    #pragma unroll
    for (int i = 0; i < 4; ++i) {
        #pragma unroll
        for (int r = 0; r < 4; ++r) {
            int row_g = rb + wro + i * 16 + kq * 4 + r;
            float rt_ = rowTerm[row_g];
            unsigned long long best = ~0ull;
            #pragma unroll
            for (int j = 0; j < 8; ++j) {
                float sq = rt_ + cT[j] - 2.0f * acc[i][j][r] + de2;
                sq = fmaxf(sq, 0.0f);
                float dist = sqrtf(sq);
                unsigned long long key =
                    ((unsigned long long)__float_as_uint(dist) << 32) |
                    (unsigned int)(cb + wco + j * 16 + c16);
                best = umin64(best, key);
            }
            #pragma unroll
            for (int m = 1; m <= 8; m <<= 1) {
                unsigned long long o =
                    (unsigned long long)__shfl_xor((long long)best, m, 64);
                best = umin64(best, o);
            }
            if (c16 == 0) atomicMin(&keys[row_g], best);
        }
    }
}

// ---------- fallback fp32 path (used only if ws too small) ----------
__global__ void row_stats(const float* __restrict__ x, float* __restrict__ rowTerm) {
    int b = blockIdx.x;
    const float* xr = x + (size_t)b * D_;
    int t = threadIdx.x;
    float acc = 0.f;
    for (int i = t; i < D_; i += 256) {
        float v = xr[i];
        acc += v * v + 2.0f * EPS_ * v;
    }
    for (int off = 32; off; off >>= 1) acc += __shfl_down(acc, off, 64);
    __shared__ float s[4];
    if ((t & 63) == 0) s[t >> 6] = acc;
    __syncthreads();
    if (t == 0) rowTerm[b] = s[0] + s[1] + s[2] + s[3];
}

__global__ void col_stats(const float* __restrict__ w, float* __restrict__ colTerm) {
    int m = blockIdx.x * 256 + threadIdx.x;
    int d0 = blockIdx.y * 64;
    const float* p = w + (size_t)d0 * M_ + m;
    float acc = 0.f;
    #pragma unroll 8
    for (int d = 0; d < 64; ++d) {
        float v = p[(size_t)d * M_];
        acc += v * v - 2.0f * EPS_ * v;
    }
    atomicAdd(&colTerm[m], acc);
}

__global__ __launch_bounds__(256, 2) void som_gemm(
    const float* __restrict__ A, const float* __restrict__ Wt,
    const float* __restrict__ rowTerm, const float* __restrict__ colTerm,
    unsigned long long* __restrict__ keys)
{
    __shared__ float As[8][128];
    __shared__ float Bs[8][128];
    const int t  = threadIdx.x;
    const int rb = blockIdx.y * 128;
    const int cb = blockIdx.x * 128;
    const int tx = t & 15;
    const int ty = t >> 4;
    float acc[8][8];
    #pragma unroll
    for (int i = 0; i < 8; ++i)
        #pragma unroll
        for (int j = 0; j < 8; ++j) acc[i][j] = 0.f;
    const int la_row = t >> 1, la_k = (t & 1) * 4;
    const int lb_k = t >> 5, lb_n = (t & 31) * 4;
    const float* Aptr = A + (size_t)(rb + la_row) * D_ + la_k;
    const float* Bptr = Wt + (size_t)lb_k * M_ + cb + lb_n;
    for (int k0 = 0; k0 < D_; k0 += 8) {
        float4 av = *(const float4*)(Aptr + k0);
        float4 bv = *(const float4*)(Bptr + (size_t)k0 * M_);
        __syncthreads();
        As[la_k + 0][la_row] = av.x;
        As[la_k + 1][la_row] = av.y;
        As[la_k + 2][la_row] = av.z;
        As[la_k + 3][la_row] = av.w;
        *(float4*)&Bs[lb_k][lb_n] = bv;
        __syncthreads();
        #pragma unroll
        for (int k = 0; k < 8; ++k) {
            float a[8], b[8];
            #pragma unroll
            for (int i = 0; i < 8; ++i) a[i] = As[k][ty * 8 + i];
            #pragma unroll
            for (int j = 0; j < 8; ++j) b[j] = Bs[k][tx * 8 + j];
            #pragma unroll
            for (int i = 0; i < 8; ++i)
                #pragma unroll
                for (int j = 0; j < 8; ++j) acc[i][j] += a[i] * b[j];
        }
    }
    float rT[8], cT[8];
    #pragma unroll
    for (int i = 0; i < 8; ++i) rT[i] = rowTerm[rb + ty * 8 + i];
    #pragma unroll
    for (int j = 0; j < 8; ++j) cT[j] = colTerm[cb + tx * 8 + j];
    const float de2 = (float)D_ * EPS_ * EPS_;
    #pragma unroll
    for (int i = 0; i < 8; ++i) {
        unsigned long long best = ~0ull;
        #pragma unroll
        for (int j = 0; j < 8; ++j) {
            float sq = rT[i] + cT[j] - 2.0f * acc[i][j] + de2;
            sq = fmaxf(sq, 0.0f);
            float dist = sqrtf(sq);
            unsigned long long key =
                ((unsigned long long)__float_as_uint(dist) << 32) |
                (unsigned int)(cb + tx * 8 + j);
            best = umin64(best, key);
        }
        #pragma unroll
        for (int msk = 1; msk <= 8; msk <<= 1) {
            unsigned long long o = __shfl_xor((long long)best, msk, 64);
            best = umin64(best, (unsigned long long)o);
        }
        if (tx == 0) atomicMin(&keys[rb + ty * 8 + i], best);
    }
}

// ---------- finalize: 8 blocks of 256 rows ----------
__global__ void finalize(const unsigned long long* __restrict__ keys,
                         const float* __restrict__ loc,
                         float* __restrict__ out)
{
    int t = threadIdx.x;
    int r = blockIdx.x * 256 + t;
    unsigned long long k = keys[r];
    unsigned int idx = (unsigned int)(k & 0xFFFFFFFFu);
    float dist = __uint_as_float((unsigned int)(k >> 32));
    out[r] = (float)idx;
    out[B_ + 2 * r]     = loc[2 * idx];
    out[B_ + 2 * r + 1] = loc[2 * idx + 1];
    float sum = dist;
    for (int off = 32; off; off >>= 1) sum += __shfl_down(sum, off, 64);
    __shared__ float s[4];
    if ((t & 63) == 0) s[t >> 6] = sum;
    __syncthreads();
    if (t == 0) atomicAdd(&out[3 * B_], (s[0] + s[1] + s[2] + s[3]) / (float)B_);
}

extern "C" void kernel_launch(void* const* d_in, const int* in_sizes, int n_in,
                              void* d_out, int out_size, void* d_ws, size_t ws_size,
                              hipStream_t stream)
{
    const float* x   = (const float*)d_in[0];
    const float* w   = (const float*)d_in[1];
    const float* loc = (const float*)d_in[2];
    float* out = (float*)d_out;

    char* ws = (char*)d_ws;
    unsigned long long* keys = (unsigned long long*)ws;   // 16 KB
    float* rowTerm = (float*)(ws + (16 << 10));           //  8 KB
    float* colPart = (float*)(ws + (24 << 10));           // 512 KB (8 planes)
    _Float16* xh  = (_Float16*)(ws + (1ull << 20));       //  4 MB
    _Float16* xl  = (_Float16*)(ws + (5ull << 20));       //  4 MB
    _Float16* wth = (_Float16*)(ws + (9ull << 20));       // 32 MB
    _Float16* wtl = (_Float16*)(ws + (41ull << 20));      // 32 MB
    const size_t NEED = 73ull << 20;

    if (ws_size >= NEED) {
        prep<<<2304, 256, 0, stream>>>(x, w, xh, xl, wth, wtl,
                                       rowTerm, colPart, keys, out);
        som_mfma<<<512, 512, 131072, stream>>>(
            xh, xl, wth, wtl, rowTerm, colPart, keys);
    } else {
        hipMemsetAsync(keys, 0xFF, B_ * sizeof(unsigned long long), stream);
        hipMemsetAsync(colPart, 0, M_ * sizeof(float), stream);
        hipMemsetAsync(out + 3 * B_, 0, sizeof(float), stream);
        row_stats<<<B_, 256, 0, stream>>>(x, rowTerm);
        col_stats<<<dim3(M_ / 256, D_ / 64), 256, 0, stream>>>(w, colPart);
        som_gemm<<<dim3(M_ / 128, B_ / 128), 256, 0, stream>>>(
            x, w, rowTerm, colPart, keys);
    }
    finalize<<<8, 256, 0, stream>>>(keys, loc, out);
}

// Round 7
// 297.352 us; speedup vs baseline: 2.0840x; 1.0214x over previous
//
#include <hip/hip_runtime.h>
#include <cstdint>
#include <cstddef>

// SOM BMU: dists[b,m] = ||x[b] - W[:,m] + eps||, argmin/min over m.
//   sq = rowTerm[b] + colTerm[m] - 2*dot(x[b],W[:,m]) + D*eps^2
// dot via split-precision f16 MFMA (xh.wh + xh.wl + xl.wh, ~2^-22 rel err).
// Pre-swizzled staging format (written by prep):
//   addr16(r,c) = (r>>4)*32768 + (c>>2)*1024 + (c&3)*256 + (r&15)*16
// R9: XCD swizzle (kept). R10: prep 2304 blocks (kept). R11: colPart (kept).
// R12-R14 measured the staging law: per-CU GLDS fill rate ~= 8 B/cyc PER
//   RESIDENT BLOCK-STREAM (R6 1blk: 8.2; R2 2blk: 13.6; m97 3blk: 22.8).
//   Schedule shape (drain vs counted-vmcnt) is second-order; stream count is
//   the limiter. R5 lesson: VGPR+AGPR budget vs launch_bounds -> spill.
// R15 (this round): maximize streams. 128x128 tile, 4 waves, single 32KB
//   buffer, m97 2-barrier loop (R2-proven body, R4-proven addressing),
//   __launch_bounds__(256,4): acc 64 AGPR + 64 VGPR (R4 measured) = 128 =
//   4 waves/SIMD knee -> 4 blocks/CU (LDS 4x32=128<=160KB). Grid 2048 =
//   2 exact rounds. Staging 2.15GB at ~32 B/cyc/CU -> ~110-140us; MFMA
//   floor 99us.
// Argmin via packed u64 key (dist_bits<<32 | m) + atomicMin.

#define B_  2048
#define D_  1024
#define M_  16384
#define EPS_ 1e-6f

typedef _Float16 v8h __attribute__((ext_vector_type(8)));
typedef float    v4f __attribute__((ext_vector_type(4)));

static __device__ __forceinline__ unsigned long long umin64(unsigned long long a,
                                                            unsigned long long b) {
    return a < b ? a : b;
}

// swizzled 16B-chunk address: row r, k-chunk c (8 f16 per chunk)
static __device__ __forceinline__ size_t addr16(int r, int c) {
    return (size_t)(r >> 4) * 32768 + (size_t)(c >> 2) * 1024 +
           (size_t)(c & 3) * 256 + (size_t)(r & 15) * 16;
}

#define GLDS16(g, l)                                                            \
    __builtin_amdgcn_global_load_lds(                                           \
        (const __attribute__((address_space(1))) void*)(g),                     \
        (__attribute__((address_space(3))) void*)(l), 16, 0, 0)

// ---------- fused prep ----------
// blocks 0..2047:    W-path. block = (col-group mg = blk>>3: 64 cols) x
//                    (d-chunk dc = blk&7: 128 d). One col per thread per wave,
//                    4 waves each cover 32 d. Writes colPart[dc][m] (no atomics).
// blocks 2048..2303: x-path. 8 rows each, one row per 32-lane half-wave.
//                    x-block 0 also inits keys + loss slot.
__global__ __launch_bounds__(256) void prep(
    const float* __restrict__ x, const float* __restrict__ W,
    _Float16* __restrict__ xh, _Float16* __restrict__ xl,
    _Float16* __restrict__ wth, _Float16* __restrict__ wtl,
    float* __restrict__ rowTerm, float* __restrict__ colPart,
    unsigned long long* __restrict__ keys, float* __restrict__ out)
{
    const int t = threadIdx.x;
    const int blk = blockIdx.x;
    if (blk < 2048) {
        __shared__ float cpart[4][64];
        const int mg = blk >> 3, dc = blk & 7;
        const int m_local = t & 63;
        const int wq = t >> 6;
        const int m = mg * 64 + m_local;
        const float* wp = W + m;
        float part = 0.f;
        #pragma unroll
        for (int cl = 0; cl < 4; ++cl) {
            const int c = dc * 16 + wq * 4 + cl;     // k-chunk (8 d each)
            const int d0 = c * 8;
            float vv[8];
            #pragma unroll
            for (int e = 0; e < 8; ++e)
                vv[e] = wp[(size_t)(d0 + e) * M_];   // wave = 256B coalesced
            v8h h, l;
            #pragma unroll
            for (int e = 0; e < 8; ++e) {
                _Float16 hi = (_Float16)vv[e];
                h[e] = hi; l[e] = (_Float16)(vv[e] - (float)hi);
                part += vv[e] * vv[e] - 2.0f * EPS_ * vv[e];
            }
            const size_t a = addr16(m, c);
            *(v8h*)((char*)wth + a) = h;             // lanes 0-15: 256B contig
            *(v8h*)((char*)wtl + a) = l;
        }
        cpart[wq][m_local] = part;
        __syncthreads();
        if (t < 64)
            colPart[(size_t)dc * M_ + mg * 64 + t] =
                cpart[0][t] + cpart[1][t] + cpart[2][t] + cpart[3][t];
    } else {
        const int xb = blk - 2048;
        const int w = t >> 6, L = t & 63;
        const int hl = L & 31;
        const int r = xb * 8 + 2 * w + (L >> 5);
        const float* xr = x + (size_t)r * D_;
        float part = 0.f;
        #pragma unroll
        for (int i = 0; i < 4; ++i) {
            const int c = 32 * i + hl;               // half-wave = 1KB coalesced
            float4 q1 = *(const float4*)(xr + 8 * c);
            float4 q2 = *(const float4*)(xr + 8 * c + 4);
            float vv[8] = {q1.x, q1.y, q1.z, q1.w, q2.x, q2.y, q2.z, q2.w};
            v8h h, l;
            #pragma unroll
            for (int e = 0; e < 8; ++e) {
                _Float16 hi = (_Float16)vv[e];
                h[e] = hi; l[e] = (_Float16)(vv[e] - (float)hi);
                part += vv[e] * vv[e] + 2.0f * EPS_ * vv[e];
            }
            const size_t a = addr16(r, c);
            *(v8h*)((char*)xh + a) = h;
            *(v8h*)((char*)xl + a) = l;
        }
        #pragma unroll
        for (int msk = 1; msk <= 16; msk <<= 1)
            part += __shfl_xor(part, msk, 64);       // stays within 32-lane half
        if (hl == 0) rowTerm[r] = part;
        if (xb == 0) {
            for (int i = t; i < B_; i += 256) keys[i] = ~0ull;
            if (t == 0) out[3 * B_] = 0.f;
        }
    }
}

// ---------- main MFMA distance GEMM + argmin ----------
// 128x128 block tile, 4 waves (2x2, each 64 rows x 64 cols), BK=32.
// Single 32KB buffer, m97 2-barrier loop, 4 blocks/CU (4 staging streams).
__global__ __launch_bounds__(256, 4) void som_mfma(
    const _Float16* __restrict__ xh, const _Float16* __restrict__ xl,
    const _Float16* __restrict__ wth, const _Float16* __restrict__ wtl,
    const float* __restrict__ rowTerm, const float* __restrict__ colPart,
    unsigned long long* __restrict__ keys)
{
    __shared__ __align__(16) char smem[32768];   // Ah 8K | Al 8K | Bh 8K | Bl 8K
    _Float16* Ah = (_Float16*)smem;
    _Float16* Al = (_Float16*)(smem + 8192);
    _Float16* Bh = (_Float16*)(smem + 16384);
    _Float16* Bl = (_Float16*)(smem + 24576);

    const int t = threadIdx.x;
    const int g = blockIdx.x;                      // 0..2047
    // XCD swizzle: xcd = g&7; all 16 row-tiles of a col-tile on one XCD.
    // bijective: g = (ct&7) + 8*rt + 128*(ct>>3)
    const int ct = (g & 7) + 8 * (g >> 7);         // col-tile 0..127
    const int rt = (g >> 3) & 15;                  // row-tile 0..15
    const int cb = ct * 128;
    const int rb = rt * 128;
    const int L = t & 63, w = t >> 6;
    const int wro = (w >> 1) * 64;
    const int wco = (w & 1) * 64;
    const int c16 = L & 15, kq = L >> 4;

    // staging: wave w covers groups {w, w+4} of each of the 4 planes (8 GLDS)
    const int lane16 = L * 16;
    const int ldsw = w * 1024;                    // wave-uniform LDS base
    const size_t abase0 = (size_t)((rb >> 4) + w) * 32768 + lane16;
    const size_t abase1 = abase0 + 4ull * 32768;
    const size_t bbase0 = (size_t)((cb >> 4) + w) * 32768 + lane16;
    const size_t bbase1 = bbase0 + 4ull * 32768;

    const char* pxh = (const char*)xh;
    const char* pxl = (const char*)xl;
    const char* pwh = (const char*)wth;
    const char* pwl = (const char*)wtl;

    v4f acc[4][4];
    #pragma unroll
    for (int i = 0; i < 4; ++i)
        #pragma unroll
        for (int j = 0; j < 4; ++j) acc[i][j] = (v4f){0.f, 0.f, 0.f, 0.f};

    // fragment read offsets (f16 units): group grp -> grp*512 + lofs
    // lofs = chunk(L>>4)*128 + row(L&15)*8  (conflict-free, measured 0)
    const int lofs = kq * 128 + c16 * 8;
    int ia[4], ibx[4];
    #pragma unroll
    for (int i = 0; i < 4; ++i) ia[i] = ((wro >> 4) + i) * 512 + lofs;
    #pragma unroll
    for (int j = 0; j < 4; ++j) ibx[j] = ((wco >> 4) + j) * 512 + lofs;

    for (int S = 0; S < 32; ++S) {
        const size_t ko = (size_t)S * 1024;
        __syncthreads();                          // prior step's ds_reads done
        GLDS16(pxh + abase0 + ko, smem + ldsw);
        GLDS16(pxh + abase1 + ko, smem + 4096 + ldsw);
        GLDS16(pxl + abase0 + ko, smem + 8192 + ldsw);
        GLDS16(pxl + abase1 + ko, smem + 12288 + ldsw);
        GLDS16(pwh + bbase0 + ko, smem + 16384 + ldsw);
        GLDS16(pwh + bbase1 + ko, smem + 20480 + ldsw);
        GLDS16(pwl + bbase0 + ko, smem + 24576 + ldsw);
        GLDS16(pwl + bbase1 + ko, smem + 28672 + ldsw);
        __syncthreads();                          // drain: buffer staged

        v8h ah[4], al4[4], bh4[4], bl4[4];
        #pragma unroll
        for (int i = 0; i < 4; ++i) {
            ah[i]  = *(const v8h*)(Ah + ia[i]);
            al4[i] = *(const v8h*)(Al + ia[i]);
        }
        #pragma unroll
        for (int j = 0; j < 4; ++j) {
            bh4[j] = *(const v8h*)(Bh + ibx[j]);
            bl4[j] = *(const v8h*)(Bl + ibx[j]);
        }
        #pragma unroll
        for (int i = 0; i < 4; ++i)
            #pragma unroll
            for (int j = 0; j < 4; ++j) {
                acc[i][j] = __builtin_amdgcn_mfma_f32_16x16x32_f16(ah[i],  bh4[j], acc[i][j], 0, 0, 0);
                acc[i][j] = __builtin_amdgcn_mfma_f32_16x16x32_f16(ah[i],  bl4[j], acc[i][j], 0, 0, 0);
                acc[i][j] = __builtin_amdgcn_mfma_f32_16x16x32_f16(al4[i], bh4[j], acc[i][j], 0, 0, 0);
            }
    }

    // epilogue: C/D layout col=lane&15, row=(lane>>4)*4+reg  [verified m89/m91]
    float cT[4];
    #pragma unroll
    for (int j = 0; j < 4; ++j) {
        const int col = cb + wco + j * 16 + c16;
        float s = 0.f;
        #pragma unroll
        for (int p = 0; p < 8; ++p) s += colPart[(size_t)p * M_ + col];
        cT[j] = s;
    }
    const float de2 = (float)D_ * EPS_ * EPS_;
    #pragma unroll
    for (int i = 0; i < 4; ++i) {
        #pragma unroll
        for (int r = 0; r < 4; ++r) {
            int row_g = rb + wro + i * 16 + kq * 4 + r;
            float rt_ = rowTerm[row_g];
            unsigned long long best = ~0ull;
            #pragma unroll
            for (int j = 0; j < 4; ++j) {
                float sq = rt_ + cT[j] - 2.0f * acc[i][j][r] + de2;
                sq = fmaxf(sq, 0.0f);
                float dist = sqrtf(sq);
                unsigned long long key =
                    ((unsigned long long)__float_as_uint(dist) << 32) |
                    (unsigned int)(cb + wco + j * 16 + c16);
                best = umin64(best, key);
            }
            #pragma unroll
            for (int m = 1; m <= 8; m <<= 1) {
                unsigned long long o =
                    (unsigned long long)__shfl_xor((long long)best, m, 64);
                best = umin64(best, o);
            }
            if (c16 == 0) atomicMin(&keys[row_g], best);
        }
    }
}

// ---------- fallback fp32 path (used only if ws too small) ----------
__global__ void row_stats(const float* __restrict__ x, float* __restrict__ rowTerm) {
    int b = blockIdx.x;
    const float* xr = x + (size_t)b * D_;
    int t = threadIdx.x;
    float acc = 0.f;
    for (int i = t; i < D_; i += 256) {
        float v = xr[i];
        acc += v * v + 2.0f * EPS_ * v;
    }
    for (int off = 32; off; off >>= 1) acc += __shfl_down(acc, off, 64);
    __shared__ float s[4];
    if ((t & 63) == 0) s[t >> 6] = acc;
    __syncthreads();
    if (t == 0) rowTerm[b] = s[0] + s[1] + s[2] + s[3];
}

__global__ void col_stats(const float* __restrict__ w, float* __restrict__ colTerm) {
    int m = blockIdx.x * 256 + threadIdx.x;
    int d0 = blockIdx.y * 64;
    const float* p = w + (size_t)d0 * M_ + m;
    float acc = 0.f;
    #pragma unroll 8
    for (int d = 0; d < 64; ++d) {
        float v = p[(size_t)d * M_];
        acc += v * v - 2.0f * EPS_ * v;
    }
    atomicAdd(&colTerm[m], acc);
}

__global__ __launch_bounds__(256, 2) void som_gemm(
    const float* __restrict__ A, const float* __restrict__ Wt,
    const float* __restrict__ rowTerm, const float* __restrict__ colTerm,
    unsigned long long* __restrict__ keys)
{
    __shared__ float As[8][128];
    __shared__ float Bs[8][128];
    const int t  = threadIdx.x;
    const int rb = blockIdx.y * 128;
    const int cb = blockIdx.x * 128;
    const int tx = t & 15;
    const int ty = t >> 4;
    float acc[8][8];
    #pragma unroll
    for (int i = 0; i < 8; ++i)
        #pragma unroll
        for (int j = 0; j < 8; ++j) acc[i][j] = 0.f;
    const int la_row = t >> 1, la_k = (t & 1) * 4;
    const int lb_k = t >> 5, lb_n = (t & 31) * 4;
    const float* Aptr = A + (size_t)(rb + la_row) * D_ + la_k;
    const float* Bptr = Wt + (size_t)lb_k * M_ + cb + lb_n;
    for (int k0 = 0; k0 < D_; k0 += 8) {
        float4 av = *(const float4*)(Aptr + k0);
        float4 bv = *(const float4*)(Bptr + (size_t)k0 * M_);
        __syncthreads();
        As[la_k + 0][la_row] = av.x;
        As[la_k + 1][la_row] = av.y;
        As[la_k + 2][la_row] = av.z;
        As[la_k + 3][la_row] = av.w;
        *(float4*)&Bs[lb_k][lb_n] = bv;
        __syncthreads();
        #pragma unroll
        for (int k = 0; k < 8; ++k) {
            float a[8], b[8];
            #pragma unroll
            for (int i = 0; i < 8; ++i) a[i] = As[k][ty * 8 + i];
            #pragma unroll
            for (int j = 0; j < 8; ++j) b[j] = Bs[k][tx * 8 + j];
            #pragma unroll
            for (int i = 0; i < 8; ++i)
                #pragma unroll
                for (int j = 0; j < 8; ++j) acc[i][j] += a[i] * b[j];
        }
    }
    float rT[8], cT[8];
    #pragma unroll
    for (int i = 0; i < 8; ++i) rT[i] = rowTerm[rb + ty * 8 + i];
    #pragma unroll
    for (int j = 0; j < 8; ++j) cT[j] = colTerm[cb + tx * 8 + j];
    const float de2 = (float)D_ * EPS_ * EPS_;
    #pragma unroll
    for (int i = 0; i < 8; ++i) {
        unsigned long long best = ~0ull;
        #pragma unroll
        for (int j = 0; j < 8; ++j) {
            float sq = rT[i] + cT[j] - 2.0f * acc[i][j] + de2;
            sq = fmaxf(sq, 0.0f);
            float dist = sqrtf(sq);
            unsigned long long key =
                ((unsigned long long)__float_as_uint(dist) << 32) |
                (unsigned int)(cb + tx * 8 + j);
            best = umin64(best, key);
        }
        #pragma unroll
        for (int msk = 1; msk <= 8; msk <<= 1) {
            unsigned long long o = __shfl_xor((long long)best, msk, 64);
            best = umin64(best, (unsigned long long)o);
        }
        if (tx == 0) atomicMin(&keys[rb + ty * 8 + i], best);
    }
}

// ---------- finalize: 8 blocks of 256 rows ----------
__global__ void finalize(const unsigned long long* __restrict__ keys,
                         const float* __restrict__ loc,
                         float* __restrict__ out)
{
    int t = threadIdx.x;
    int r = blockIdx.x * 256 + t;
    unsigned long long k = keys[r];
    unsigned int idx = (unsigned int)(k & 0xFFFFFFFFu);
    float dist = __uint_as_float((unsigned int)(k >> 32));
    out[r] = (float)idx;
    out[B_ + 2 * r]     = loc[2 * idx];
    out[B_ + 2 * r + 1] = loc[2 * idx + 1];
    float sum = dist;
    for (int off = 32; off; off >>= 1) sum += __shfl_down(sum, off, 64);
    __shared__ float s[4];
    if ((t & 63) == 0) s[t >> 6] = sum;
    __syncthreads();
    if (t == 0) atomicAdd(&out[3 * B_], (s[0] + s[1] + s[2] + s[3]) / (float)B_);
}

extern "C" void kernel_launch(void* const* d_in, const int* in_sizes, int n_in,
                              void* d_out, int out_size, void* d_ws, size_t ws_size,
                              hipStream_t stream)
{
    const float* x   = (const float*)d_in[0];
    const float* w   = (const float*)d_in[1];
    const float* loc = (const float*)d_in[2];
    float* out = (float*)d_out;

    char* ws = (char*)d_ws;
    unsigned long long* keys = (unsigned long long*)ws;   // 16 KB
    float* rowTerm = (float*)(ws + (16 << 10));           //  8 KB
    float* colPart = (float*)(ws + (24 << 10));           // 512 KB (8 planes)
    _Float16* xh  = (_Float16*)(ws + (1ull << 20));       //  4 MB
    _Float16* xl  = (_Float16*)(ws + (5ull << 20));       //  4 MB
    _Float16* wth = (_Float16*)(ws + (9ull << 20));       // 32 MB
    _Float16* wtl = (_Float16*)(ws + (41ull << 20));      // 32 MB
    const size_t NEED = 73ull << 20;

    if (ws_size >= NEED) {
        prep<<<2304, 256, 0, stream>>>(x, w, xh, xl, wth, wtl,
                                       rowTerm, colPart, keys, out);
        som_mfma<<<2048, 256, 0, stream>>>(
            xh, xl, wth, wtl, rowTerm, colPart, keys);
    } else {
        hipMemsetAsync(keys, 0xFF, B_ * sizeof(unsigned long long), stream);
        hipMemsetAsync(colPart, 0, M_ * sizeof(float), stream);
        hipMemsetAsync(out + 3 * B_, 0, sizeof(float), stream);
        row_stats<<<B_, 256, 0, stream>>>(x, rowTerm);
        col_stats<<<dim3(M_ / 256, D_ / 64), 256, 0, stream>>>(w, colPart);
        som_gemm<<<dim3(M_ / 128, B_ / 128), 256, 0, stream>>>(
            x, w, rowTerm, colPart, keys);
    }
    finalize<<<8, 256, 0, stream>>>(keys, loc, out);
}